// Round 12
// baseline (182.480 us; speedup 1.0000x reference)
//
#include <hip/hip_runtime.h>
#include <hip/hip_bf16.h>

// Problem constants (B=4, S=2048 -> 8192 tokens; D=O=1024; E=8; top-2)
#define NTOK 8192
#define DDIM 1024
#define ODIM 1024
#define NEXP 8
#define BK   32
#define NKT  (DDIM / BK)     // 32 K-tiles

typedef __attribute__((ext_vector_type(8))) short short8;
typedef __attribute__((ext_vector_type(4))) float f32x4;

// ---- workspace layout (bytes) ----
#define CNT_OFF   0u                               // 16 ints (expert x rank)
#define SC_OFF    (4u * 1024u)                     // 8192*2 floats
#define LIST_OFF  (128u * 1024u)                   // 16*8192 ints = 512 KiB
#define XH_OFF    (1u << 20)                       // bf16 x, 16 MiB
#define WH_OFF    ((1u << 20) + 16u*1024u*1024u)   // bf16 W, 16 MiB
#define O2_OFF    ((1u << 20) + 32u*1024u*1024u)   // rank-1 accum, 32 MiB
#define WS_NEED   ((size_t)O2_OFF + (size_t)NTOK * ODIM * 4u)

__device__ inline unsigned short f2bf(float f) {
    unsigned int u = __float_as_uint(f);
    unsigned int r = (u + 0x7FFFu + ((u >> 16) & 1u)) >> 16;   // RNE
    return (unsigned short)r;
}

__device__ inline void glds16(const unsigned short* g, unsigned short* l) {
    __builtin_amdgcn_global_load_lds(
        (const __attribute__((address_space(1))) unsigned int*)g,
        (__attribute__((address_space(3))) unsigned int*)l, 16, 0, 0);
}

// W fp32->bf16; block 0 also zeroes the 16 expert-x-rank counts (pre-gate)
__global__ void k_cvtw(const float4* __restrict__ src, ushort4* __restrict__ dst,
                       int n4, int* __restrict__ counts) {
    if (blockIdx.x == 0 && threadIdx.x < 16) counts[threadIdx.x] = 0;
    int i = blockIdx.x * blockDim.x + threadIdx.x;
    if (i >= n4) return;
    float4 v = src[i];
    ushort4 o;
    o.x = f2bf(v.x); o.y = f2bf(v.y); o.z = f2bf(v.z); o.w = f2bf(v.w);
    dst[i] = o;
}

// Gating (round-6 proven form): 1024 blocks x 8 tokens (2 per wave). No VGPR
// clamp (round-5 spill lesson). fp64 dot+butterfly decides top-k; fp32 expf
// weights. 16 lists (expert x rank), block-aggregated scatter. Fused bf16
// conversion of x. Bias is folded into the GEMM epilogue.
__global__ __launch_bounds__(256) void k_gate(
    const float* __restrict__ x, const float* __restrict__ Wg,
    const float* __restrict__ bg, float* __restrict__ scores2,
    int* __restrict__ lists, int* __restrict__ counts,
    unsigned short* __restrict__ xh)
{
    __shared__ unsigned char s_eid[16];     // 8 tokens * 2 entries
    const int tid = threadIdx.x, wave = tid >> 6, lane = tid & 63;
    const int tblk = blockIdx.x * 8;

    #pragma unroll 1
    for (int ti = 0; ti < 2; ti++) {
        const int t = tblk + wave * 2 + ti;
        const float* xr = x + (size_t)t * DDIM;
        float4 xv[4];
        #pragma unroll
        for (int i = 0; i < 4; i++)
            xv[i] = *(const float4*)&xr[lane * 4 + 256 * i];

        unsigned short* xhr = xh + (size_t)t * DDIM;
        #pragma unroll
        for (int i = 0; i < 4; i++) {
            ushort4 h;
            h.x = f2bf(xv[i].x); h.y = f2bf(xv[i].y);
            h.z = f2bf(xv[i].z); h.w = f2bf(xv[i].w);
            *(ushort4*)&xhr[lane * 4 + 256 * i] = h;
        }

        double lg[NEXP];
        #pragma unroll
        for (int e = 0; e < NEXP; e++) {
            const float* wr = Wg + (size_t)e * DDIM;
            double a = 0.0;
            #pragma unroll
            for (int i = 0; i < 4; i++) {
                float4 wv = *(const float4*)&wr[lane * 4 + 256 * i];
                a += (double)xv[i].x * (double)wv.x + (double)xv[i].y * (double)wv.y
                   + (double)xv[i].z * (double)wv.z + (double)xv[i].w * (double)wv.w;
            }
            #pragma unroll
            for (int off = 32; off > 0; off >>= 1) a += __shfl_xor(a, off);
            lg[e] = a + (double)bg[e];
        }

        int i0 = -1, i1 = -1;
        double best = -1e300, sec = -1e300;
        #pragma unroll
        for (int e = 0; e < NEXP; e++) {
            double v = lg[e];
            if (v > best) { sec = best; i1 = i0; best = v; i0 = e; }
            else if (v > sec) { sec = v; i1 = e; }
        }
        float sum = 0.f;
        #pragma unroll
        for (int e = 0; e < NEXP; e++) sum += expf((float)(lg[e] - best));
        float s0 = 1.f / sum;
        float s1 = expf((float)(sec - best)) / sum;

        if (lane == 0) {
            scores2[t * 2 + 0] = s0;
            scores2[t * 2 + 1] = s1;
            int le = (wave * 2 + ti) * 2;
            s_eid[le + 0] = (unsigned char)i0;
            s_eid[le + 1] = (unsigned char)i1;
        }
    }
    __syncthreads();

    // 16 owners: e = tid&7, rank = tid>>3; one global atomic per (block,owner)
    if (tid < 16) {
        int e = tid & 7, kk = tid >> 3;
        int c = 0;
        #pragma unroll
        for (int j = 0; j < 8; j++) c += (s_eid[j * 2 + kk] == e);
        if (c) {
            int p = atomicAdd(&counts[tid], c);
            #pragma unroll
            for (int j = 0; j < 8; j++)
                if (s_eid[j * 2 + kk] == e)
                    lists[tid * NTOK + (p++)] = (tblk + j) * 2 + kk;
        }
    }
}

// Grouped GEMM over 16 (expert x rank) lists, BLOCK-PER-TILE. 256x256 tile
// (8 waves = 2M x 4N, wave-tile 128x64), BK=32, double-buffered 64 KiB LDS,
// 1 block/CU. Rationale: per-CU staged-byte throughput is the measured bound
// (~43 B/cyc); 256^2 stages (BM+BN)*K*2B = 1 MB per 134 MFLOP tile = half the
// bytes/FLOP of 128^2. Round 10's 256^2 failed from __launch_bounds__(512,2)
// VGPR-128 clamp -> accumulator SPILL (VGPR_Count=92 < acc size proves it);
// NO min-waves clamp here. Sync skeleton = round-6 proven (__syncthreads per
// K-step, stage(t+1) after it). Swizzle for 64B rows (BK=32): bits 4-5 only:
//   phys_byte = logical_byte ^ ((row&3)<<4)   [within-row involution]
// applied to BOTH glds source (inverse) and ds_read offsets; 16-lane column
// reads spread 4 slots x (row&1) banksets -> 2-way = free.
// Epilogue: bias folded, pure stores (rank-0 -> out, rank-1 -> out2).
__global__ __launch_bounds__(512) void k_gemm(
    const unsigned short* __restrict__ xh, const unsigned short* __restrict__ wh,
    const int* __restrict__ counts, const int* __restrict__ lists,
    const float* __restrict__ scores2, const float* __restrict__ bias,
    float* __restrict__ out, float* __restrict__ out2, int listLo, int listHi)
{
    __shared__ __align__(16) unsigned short As[2][256 * BK];   // 32 KiB
    __shared__ __align__(16) unsigned short Bs[2][256 * BK];   // 32 KiB

    // bijective chunked XCD swizzle (gridDim % 8 == 0)
    const int nwg = (int)gridDim.x;
    int bid = ((int)blockIdx.x & 7) * (nwg >> 3) + ((int)blockIdx.x >> 3);

    int li = -1, mt = 0, nt = 0, cnt = 0;
    #pragma unroll
    for (int i = 0; i < 16; i++) {
        if (i < listLo || i >= listHi) continue;
        int c = counts[i];
        int tiles = ((c + 255) >> 8) * 4;      // 4 n-tiles (BN=256)
        if (li < 0) {
            if (bid < tiles) { li = i; mt = bid >> 2; nt = bid & 3; cnt = c; }
            else bid -= tiles;
        }
    }
    if (li < 0) return;

    const int m0 = mt * 256, n0 = nt * 256;
    const int* list = lists + li * NTOK;
    const int exp_ = li & 7;
    const unsigned short* whE = wh + (size_t)exp_ * ODIM * DDIM;
    const int tid = threadIdx.x, wid = tid >> 6, lane = tid & 63;

    // ---- staging: per thread 2 A + 2 B glds per K-step. Instr i covers
    // phys rows [i*128 + wid*16, +16); lane -> row P = base + (lane>>2),
    // slot s = lane&3. Inverse swizzle: logical slot c = s ^ (P&3).
    const int rl = lane >> 2, s4 = lane & 3;
    const unsigned short* aS[2];
    const unsigned short* bS[2];
    int dbase[2];
    #pragma unroll
    for (int i = 0; i < 2; i++) {
        const int rb = i * 128 + wid * 16;
        dbase[i] = rb * BK;                     // elems
        const int P = rb + rl;
        const int c = s4 ^ (P & 3);
        int g = m0 + P; if (g >= cnt) g = cnt - 1;
        aS[i] = xh + (size_t)(list[g] >> 1) * DDIM + c * 8;
        bS[i] = whE + (size_t)(n0 + P) * DDIM + c * 8;
    }

    // ---- fragment read byte-offsets (swizzled); wave grid 2M x 4N ----
    const int wm = wid >> 2, wn = wid & 3;
    const int fr = lane & 15, g4 = lane >> 4;
    int offA[8], offB[4];
    #pragma unroll
    for (int m = 0; m < 8; m++) {
        int R = wm * 128 + m * 16 + fr;
        offA[m] = (R * 64) + (((g4 ^ (R & 3)) << 4));
    }
    #pragma unroll
    for (int n = 0; n < 4; n++) {
        int R = wn * 64 + n * 16 + fr;
        offB[n] = (R * 64) + (((g4 ^ (R & 3)) << 4));
    }

    f32x4 acc[8][4];
    #pragma unroll
    for (int m = 0; m < 8; m++)
        #pragma unroll
        for (int n = 0; n < 4; n++)
            acc[m][n] = (f32x4){0.f, 0.f, 0.f, 0.f};

    // prologue: stage K-tile 0 into buf 0
    #pragma unroll
    for (int i = 0; i < 2; i++) {
        glds16(aS[i], &As[0][dbase[i]]);
        glds16(bS[i], &Bs[0][dbase[i]]);
    }

    int buf = 0;
    #pragma unroll 1
    for (int t = 0; t < NKT; t++) {
        __syncthreads();                 // stage(t) landed (vmcnt drain)
        if (t + 1 < NKT) {
            const int k0 = (t + 1) * BK;
            #pragma unroll
            for (int i = 0; i < 2; i++) {
                glds16(aS[i] + k0, &As[buf ^ 1][dbase[i]]);
                glds16(bS[i] + k0, &Bs[buf ^ 1][dbase[i]]);
            }
        }
        const char* ab = (const char*)&As[buf][0];
        const char* bb = (const char*)&Bs[buf][0];
        short8 af[8], bfv[4];
        #pragma unroll
        for (int m = 0; m < 8; m++) af[m] = *(const short8*)(ab + offA[m]);
        #pragma unroll
        for (int n = 0; n < 4; n++) bfv[n] = *(const short8*)(bb + offB[n]);
        #pragma unroll
        for (int m = 0; m < 8; m++)
            #pragma unroll
            for (int n = 0; n < 4; n++)
                acc[m][n] = __builtin_amdgcn_mfma_f32_16x16x32_bf16(
                    af[m], bfv[n], acc[m][n], 0, 0, 0);
        buf ^= 1;
    }

    // epilogue (C/D: col=lane&15, row=(lane>>4)*4+j); bias folded:
    // out_row = s * (acc + b[e]); pure store (rank-1 RMW only in fallback)
    const bool rank1 = (li >= 8);
    float* dstBase = (rank1 && out2 != nullptr) ? out2 : out;
    const bool rmw = rank1 && (out2 == nullptr);
    const float* brow = bias + (size_t)exp_ * ODIM + n0 + wn * 64 + fr;
    float bv[4];
    #pragma unroll
    for (int n = 0; n < 4; n++) bv[n] = brow[n * 16];

    #pragma unroll
    for (int m = 0; m < 8; m++) {
        #pragma unroll
        for (int j = 0; j < 4; j++) {
            int r = wm * 128 + m * 16 + g4 * 4 + j;
            int gr = m0 + r;
            if (gr < cnt) {
                int entry = list[gr];
                float s = scores2[entry];
                float* orow = dstBase + (size_t)(entry >> 1) * ODIM + n0 + wn * 64 + fr;
                if (rmw) {
                    #pragma unroll
                    for (int n = 0; n < 4; n++)
                        orow[n * 16] += s * (acc[m][n][j] + bv[n]);
                } else {
                    #pragma unroll
                    for (int n = 0; n < 4; n++)
                        orow[n * 16] = s * (acc[m][n][j] + bv[n]);
                }
            }
        }
    }
}

__global__ void k_add(float4* __restrict__ out, const float4* __restrict__ out2, int n4) {
    int i = blockIdx.x * blockDim.x + threadIdx.x;
    const int stride = gridDim.x * blockDim.x;
    #pragma unroll 1
    for (; i < n4; i += stride) {
        float4 a = out[i], c = out2[i];
        a.x += c.x; a.y += c.y; a.z += c.z; a.w += c.w;
        out[i] = a;
    }
}

extern "C" void kernel_launch(void* const* d_in, const int* in_sizes, int n_in,
                              void* d_out, int out_size, void* d_ws, size_t ws_size,
                              hipStream_t stream) {
    const float* x  = (const float*)d_in[0];
    const float* W  = (const float*)d_in[1];
    const float* b  = (const float*)d_in[2];
    const float* Wg = (const float*)d_in[3];
    const float* bg = (const float*)d_in[4];
    float* out = (float*)d_out;
    char* ws = (char*)d_ws;

    int*   counts  = (int*)(ws + CNT_OFF);    // [16]: rank0 experts, rank1 experts
    float* scores2 = (float*)(ws + SC_OFF);
    int*   lists   = (int*)(ws + LIST_OFF);   // [16][NTOK]
    unsigned short* xh = (unsigned short*)(ws + XH_OFF);
    unsigned short* wh = (unsigned short*)(ws + WH_OFF);
    float* out2 = (float*)(ws + O2_OFF);

    int n4w = NEXP * ODIM * DDIM / 4;
    k_cvtw<<<n4w / 256, 256, 0, stream>>>((const float4*)W, (ushort4*)wh, n4w, counts);

    k_gate<<<NTOK / 8, 256, 0, stream>>>(x, Wg, bg, scores2, lists, counts, xh);

    // block-per-tile: worst case sum_16 ceil(c/256)*4 <= (64+16)*4 = 320;
    // grid 320 (%8==0). 64KB LDS, ~230 VGPR (no clamp!) -> 1 block/CU, 8 waves.
    if (ws_size >= WS_NEED) {
        k_gemm<<<320, 512, 0, stream>>>(xh, wh, counts, lists, scores2, b, out, out2, 0, 16);
        k_add<<<2048, 256, 0, stream>>>((float4*)out, (const float4*)out2, NTOK * ODIM / 4);
    } else {
        k_gemm<<<320, 512, 0, stream>>>(xh, wh, counts, lists, scores2, b, out, nullptr, 0, 8);
        k_gemm<<<320, 512, 0, stream>>>(xh, wh, counts, lists, scores2, b, out, nullptr, 8, 16);
    }
}

// Round 13
// 145.037 us; speedup vs baseline: 1.2582x; 1.2582x over previous
//
#include <hip/hip_runtime.h>
#include <hip/hip_bf16.h>

// Problem constants (B=4, S=2048 -> 8192 tokens; D=O=1024; E=8; top-2)
#define NTOK 8192
#define DDIM 1024
#define ODIM 1024
#define NEXP 8
#define BK   32
#define NKT  (DDIM / BK)     // 32 K-tiles

typedef __attribute__((ext_vector_type(8))) short short8;
typedef __attribute__((ext_vector_type(4))) float f32x4;

// ---- workspace layout (bytes) ----
#define CNT_OFF   0u                               // 16 ints (expert x rank)
#define SC_OFF    (4u * 1024u)                     // 8192*2 floats
#define LIST_OFF  (128u * 1024u)                   // 16*8192 ints = 512 KiB
#define XH_OFF    (1u << 20)                       // bf16 x, 16 MiB
#define WH_OFF    ((1u << 20) + 16u*1024u*1024u)   // bf16 W, 16 MiB
#define O2_OFF    ((1u << 20) + 32u*1024u*1024u)   // rank-1 accum, 32 MiB
#define WS_NEED   ((size_t)O2_OFF + (size_t)NTOK * ODIM * 4u)

__device__ inline unsigned short f2bf(float f) {
    unsigned int u = __float_as_uint(f);
    unsigned int r = (u + 0x7FFFu + ((u >> 16) & 1u)) >> 16;   // RNE
    return (unsigned short)r;
}

__device__ inline void glds16(const unsigned short* g, unsigned short* l) {
    __builtin_amdgcn_global_load_lds(
        (const __attribute__((address_space(1))) unsigned int*)g,
        (__attribute__((address_space(3))) unsigned int*)l, 16, 0, 0);
}

// W fp32->bf16; block 0 also zeroes the 16 expert-x-rank counts (pre-gate)
__global__ void k_cvtw(const float4* __restrict__ src, ushort4* __restrict__ dst,
                       int n4, int* __restrict__ counts) {
    if (blockIdx.x == 0 && threadIdx.x < 16) counts[threadIdx.x] = 0;
    int i = blockIdx.x * blockDim.x + threadIdx.x;
    if (i >= n4) return;
    float4 v = src[i];
    ushort4 o;
    o.x = f2bf(v.x); o.y = f2bf(v.y); o.z = f2bf(v.z); o.w = f2bf(v.w);
    dst[i] = o;
}

// Gating (round-6 proven form): 1024 blocks x 8 tokens (2 per wave). No VGPR
// clamp (round-5 spill lesson). fp64 dot+butterfly decides top-k; fp32 expf
// weights. 16 lists (expert x rank), block-aggregated scatter. Fused bf16
// conversion of x. Bias is folded into the GEMM epilogue.
__global__ __launch_bounds__(256) void k_gate(
    const float* __restrict__ x, const float* __restrict__ Wg,
    const float* __restrict__ bg, float* __restrict__ scores2,
    int* __restrict__ lists, int* __restrict__ counts,
    unsigned short* __restrict__ xh)
{
    __shared__ unsigned char s_eid[16];     // 8 tokens * 2 entries
    const int tid = threadIdx.x, wave = tid >> 6, lane = tid & 63;
    const int tblk = blockIdx.x * 8;

    #pragma unroll 1
    for (int ti = 0; ti < 2; ti++) {
        const int t = tblk + wave * 2 + ti;
        const float* xr = x + (size_t)t * DDIM;
        float4 xv[4];
        #pragma unroll
        for (int i = 0; i < 4; i++)
            xv[i] = *(const float4*)&xr[lane * 4 + 256 * i];

        unsigned short* xhr = xh + (size_t)t * DDIM;
        #pragma unroll
        for (int i = 0; i < 4; i++) {
            ushort4 h;
            h.x = f2bf(xv[i].x); h.y = f2bf(xv[i].y);
            h.z = f2bf(xv[i].z); h.w = f2bf(xv[i].w);
            *(ushort4*)&xhr[lane * 4 + 256 * i] = h;
        }

        double lg[NEXP];
        #pragma unroll
        for (int e = 0; e < NEXP; e++) {
            const float* wr = Wg + (size_t)e * DDIM;
            double a = 0.0;
            #pragma unroll
            for (int i = 0; i < 4; i++) {
                float4 wv = *(const float4*)&wr[lane * 4 + 256 * i];
                a += (double)xv[i].x * (double)wv.x + (double)xv[i].y * (double)wv.y
                   + (double)xv[i].z * (double)wv.z + (double)xv[i].w * (double)wv.w;
            }
            #pragma unroll
            for (int off = 32; off > 0; off >>= 1) a += __shfl_xor(a, off);
            lg[e] = a + (double)bg[e];
        }

        int i0 = -1, i1 = -1;
        double best = -1e300, sec = -1e300;
        #pragma unroll
        for (int e = 0; e < NEXP; e++) {
            double v = lg[e];
            if (v > best) { sec = best; i1 = i0; best = v; i0 = e; }
            else if (v > sec) { sec = v; i1 = e; }
        }
        float sum = 0.f;
        #pragma unroll
        for (int e = 0; e < NEXP; e++) sum += expf((float)(lg[e] - best));
        float s0 = 1.f / sum;
        float s1 = expf((float)(sec - best)) / sum;

        if (lane == 0) {
            scores2[t * 2 + 0] = s0;
            scores2[t * 2 + 1] = s1;
            int le = (wave * 2 + ti) * 2;
            s_eid[le + 0] = (unsigned char)i0;
            s_eid[le + 1] = (unsigned char)i1;
        }
    }
    __syncthreads();

    // 16 owners: e = tid&7, rank = tid>>3; one global atomic per (block,owner)
    if (tid < 16) {
        int e = tid & 7, kk = tid >> 3;
        int c = 0;
        #pragma unroll
        for (int j = 0; j < 8; j++) c += (s_eid[j * 2 + kk] == e);
        if (c) {
            int p = atomicAdd(&counts[tid], c);
            #pragma unroll
            for (int j = 0; j < 8; j++)
                if (s_eid[j * 2 + kk] == e)
                    lists[tid * NTOK + (p++)] = (tblk + j) * 2 + kk;
        }
    }
}

// Grouped GEMM over 16 (expert x rank) lists, BLOCK-PER-TILE. Tile 256x128
// (BM=256 token rows, BN=128 cols), 512 threads = 8 waves (4M x 2N, wave-tile
// 64x64, acc[4][4] = 64 AGPR). Rationale (r12): per-CU rate is ~36% higher at
// larger tiles, but 256^2 forces 1 block/CU and ~288 tiles -> 2-round
// quantization. 256x128 keeps the big-M geometry at 48 KiB LDS + 128-reg
// budget (__launch_bounds__(512,2), the r6-proven exact-fit: 64 arch + 64
// acc) -> 2 blocks/CU co-resident, ~576 tiles on 512 slots.
// Sync skeleton = round-6 proven: one __syncthreads per K-step, stage(t+1)
// right after. Swizzle = r6's verified conflict-free form for 64B rows:
//   slot_phys = slot_log ^ ((row>>1)&3)   [+ row bit0 supplies bank-bit 6]
// applied on BOTH glds global source (inverse) and ds_read offsets.
// Epilogue: bias folded, pure stores (rank-0 -> out, rank-1 -> out2).
__global__ __launch_bounds__(512, 2) void k_gemm(
    const unsigned short* __restrict__ xh, const unsigned short* __restrict__ wh,
    const int* __restrict__ counts, const int* __restrict__ lists,
    const float* __restrict__ scores2, const float* __restrict__ bias,
    float* __restrict__ out, float* __restrict__ out2, int listLo, int listHi)
{
    __shared__ __align__(16) unsigned short As[2][256 * BK];   // 32 KiB
    __shared__ __align__(16) unsigned short Bs[2][128 * BK];   // 16 KiB

    // bijective chunked XCD swizzle (gridDim % 8 == 0)
    const int nwg = (int)gridDim.x;
    int bid = ((int)blockIdx.x & 7) * (nwg >> 3) + ((int)blockIdx.x >> 3);

    int li = -1, mt = 0, nt = 0, cnt = 0;
    #pragma unroll
    for (int i = 0; i < 16; i++) {
        if (i < listLo || i >= listHi) continue;
        int c = counts[i];
        int tiles = ((c + 255) >> 8) * 8;      // 8 n-tiles (BN=128)
        if (li < 0) {
            if (bid < tiles) { li = i; mt = bid >> 3; nt = bid & 7; cnt = c; }
            else bid -= tiles;
        }
    }
    if (li < 0) return;

    const int m0 = mt * 256, n0 = nt * 128;
    const int* list = lists + li * NTOK;
    const int exp_ = li & 7;
    const unsigned short* whE = wh + (size_t)exp_ * ODIM * DDIM;
    const int tid = threadIdx.x, wid = tid >> 6, lane = tid & 63;

    // ---- staging: per thread 2 A + 1 B glds per K-step.
    // A instr i covers rows [i*128 + wid*16, +16); B covers [wid*16, +16).
    // lane -> row P = base + (lane>>2), slot s = lane&3;
    // inverse swizzle: logical slot c = s ^ ((P>>1)&3) -> global col c*8.
    const int rl = lane >> 2, s4 = lane & 3;
    const unsigned short* aS[2];
    const unsigned short* bS;
    int dbA[2], dbB;
    #pragma unroll
    for (int i = 0; i < 2; i++) {
        const int rb = i * 128 + wid * 16;
        dbA[i] = rb * BK;
        const int P = rb + rl;
        const int c = s4 ^ ((P >> 1) & 3);
        int g = m0 + P; if (g >= cnt) g = cnt - 1;
        aS[i] = xh + (size_t)(list[g] >> 1) * DDIM + c * 8;
    }
    {
        const int rb = wid * 16;
        dbB = rb * BK;
        const int P = rb + rl;
        const int c = s4 ^ ((P >> 1) & 3);
        bS = whE + (size_t)(n0 + P) * DDIM + c * 8;
    }

    // ---- fragment read element-offsets (swizzled); wave grid 4M x 2N ----
    const int wm = wid >> 1, wn = wid & 1;
    const int fr = lane & 15, g4 = lane >> 4;
    int offA[4], offB[4];
    #pragma unroll
    for (int m = 0; m < 4; m++) {
        int R = wm * 64 + m * 16 + fr;
        offA[m] = R * BK + ((g4 ^ ((R >> 1) & 3)) * 8);
    }
    #pragma unroll
    for (int n = 0; n < 4; n++) {
        int R = wn * 64 + n * 16 + fr;
        offB[n] = R * BK + ((g4 ^ ((R >> 1) & 3)) * 8);
    }

    f32x4 acc[4][4];
    #pragma unroll
    for (int m = 0; m < 4; m++)
        #pragma unroll
        for (int n = 0; n < 4; n++)
            acc[m][n] = (f32x4){0.f, 0.f, 0.f, 0.f};

    // prologue: stage K-tile 0 into buf 0
    #pragma unroll
    for (int i = 0; i < 2; i++) glds16(aS[i], &As[0][dbA[i]]);
    glds16(bS, &Bs[0][dbB]);

    int buf = 0;
    #pragma unroll 1
    for (int t = 0; t < NKT; t++) {
        __syncthreads();                 // stage(t) landed (vmcnt drain)
        if (t + 1 < NKT) {
            const int k0 = (t + 1) * BK;
            #pragma unroll
            for (int i = 0; i < 2; i++) glds16(aS[i] + k0, &As[buf ^ 1][dbA[i]]);
            glds16(bS + k0, &Bs[buf ^ 1][dbB]);
        }
        short8 af[4], bfv[4];
        #pragma unroll
        for (int m = 0; m < 4; m++) af[m] = *(const short8*)&As[buf][offA[m]];
        #pragma unroll
        for (int n = 0; n < 4; n++) bfv[n] = *(const short8*)&Bs[buf][offB[n]];
        #pragma unroll
        for (int m = 0; m < 4; m++)
            #pragma unroll
            for (int n = 0; n < 4; n++)
                acc[m][n] = __builtin_amdgcn_mfma_f32_16x16x32_bf16(
                    af[m], bfv[n], acc[m][n], 0, 0, 0);
        buf ^= 1;
    }

    // epilogue (C/D: col=lane&15, row=(lane>>4)*4+j); bias folded:
    // out_row = s * (acc + b[e]); pure store (rank-1 RMW only in fallback)
    const bool rank1 = (li >= 8);
    float* dstBase = (rank1 && out2 != nullptr) ? out2 : out;
    const bool rmw = rank1 && (out2 == nullptr);
    const float* brow = bias + (size_t)exp_ * ODIM + n0 + wn * 64 + fr;
    float bv[4];
    #pragma unroll
    for (int n = 0; n < 4; n++) bv[n] = brow[n * 16];

    #pragma unroll
    for (int m = 0; m < 4; m++) {
        #pragma unroll
        for (int j = 0; j < 4; j++) {
            int r = wm * 64 + m * 16 + g4 * 4 + j;
            int gr = m0 + r;
            if (gr < cnt) {
                int entry = list[gr];
                float s = scores2[entry];
                float* orow = dstBase + (size_t)(entry >> 1) * ODIM + n0 + wn * 64 + fr;
                if (rmw) {
                    #pragma unroll
                    for (int n = 0; n < 4; n++)
                        orow[n * 16] += s * (acc[m][n][j] + bv[n]);
                } else {
                    #pragma unroll
                    for (int n = 0; n < 4; n++)
                        orow[n * 16] = s * (acc[m][n][j] + bv[n]);
                }
            }
        }
    }
}

__global__ void k_add(float4* __restrict__ out, const float4* __restrict__ out2, int n4) {
    int i = blockIdx.x * blockDim.x + threadIdx.x;
    const int stride = gridDim.x * blockDim.x;
    #pragma unroll 1
    for (; i < n4; i += stride) {
        float4 a = out[i], c = out2[i];
        a.x += c.x; a.y += c.y; a.z += c.z; a.w += c.w;
        out[i] = a;
    }
}

extern "C" void kernel_launch(void* const* d_in, const int* in_sizes, int n_in,
                              void* d_out, int out_size, void* d_ws, size_t ws_size,
                              hipStream_t stream) {
    const float* x  = (const float*)d_in[0];
    const float* W  = (const float*)d_in[1];
    const float* b  = (const float*)d_in[2];
    const float* Wg = (const float*)d_in[3];
    const float* bg = (const float*)d_in[4];
    float* out = (float*)d_out;
    char* ws = (char*)d_ws;

    int*   counts  = (int*)(ws + CNT_OFF);    // [16]: rank0 experts, rank1 experts
    float* scores2 = (float*)(ws + SC_OFF);
    int*   lists   = (int*)(ws + LIST_OFF);   // [16][NTOK]
    unsigned short* xh = (unsigned short*)(ws + XH_OFF);
    unsigned short* wh = (unsigned short*)(ws + WH_OFF);
    float* out2 = (float*)(ws + O2_OFF);

    int n4w = NEXP * ODIM * DDIM / 4;
    k_cvtw<<<n4w / 256, 256, 0, stream>>>((const float4*)W, (ushort4*)wh, n4w, counts);

    k_gate<<<NTOK / 8, 256, 0, stream>>>(x, Wg, bg, scores2, lists, counts, xh);

    // block-per-tile: worst case sum_16 ceil(c/256)*8 <= (64+16)*8 = 640;
    // grid 640 (%8==0). 48KB LDS + 128-reg budget -> 2 blocks/CU (1024 slots).
    if (ws_size >= WS_NEED) {
        k_gemm<<<640, 512, 0, stream>>>(xh, wh, counts, lists, scores2, b, out, out2, 0, 16);
        k_add<<<2048, 256, 0, stream>>>((float4*)out, (const float4*)out2, NTOK * ODIM / 4);
    } else {
        k_gemm<<<640, 512, 0, stream>>>(xh, wh, counts, lists, scores2, b, out, nullptr, 0, 8);
        k_gemm<<<640, 512, 0, stream>>>(xh, wh, counts, lists, scores2, b, out, nullptr, 8, 16);
    }
}